// Round 1
// baseline (191.329 us; speedup 1.0000x reference)
//
#include <hip/hip_runtime.h>

typedef short bf16x8 __attribute__((ext_vector_type(8)));
typedef float f32x4  __attribute__((ext_vector_type(4)));

__device__ __forceinline__ unsigned short f32_to_bf16(float f) {
  union { float f; unsigned int u; } v; v.f = f;
  unsigned int u = v.u;
  u += 0x7fffu + ((u >> 16) & 1u);   // round-to-nearest-even
  return (unsigned short)(u >> 16);
}
__device__ __forceinline__ float bf16lo_to_f32(unsigned int u) {
  union { unsigned int u; float f; } v; v.u = u << 16; return v.f;
}
__device__ __forceinline__ float bf16hi_to_f32(unsigned int u) {
  union { unsigned int u; float f; } v; v.u = u & 0xffff0000u; return v.f;
}

// h = x @ W.T + b, h[0,:] = 0, stored as bf16.
// Tile: BM=64 rows x BN=256 cols (full width -> x read exactly once).
// 256 threads = 4 waves; wave w computes rows 0..63 x cols [w*64, w*64+64).
__global__ __launch_bounds__(256, 2) void gin_gemm(
    const float* __restrict__ x, const float* __restrict__ W,
    const float* __restrict__ bias, unsigned short* __restrict__ h, int M) {
  __shared__ __align__(16) unsigned short As[64 * 32];   // [row][k]  4 KB
  __shared__ __align__(16) unsigned short Bs[256 * 32];  // [col][k] 16 KB

  const int tid  = threadIdx.x;
  const int wid  = tid >> 6;
  const int lane = tid & 63;
  const int row0 = blockIdx.x * 64;

  f32x4 acc[4][4] = {};  // [row-group][col-group], 64 VGPRs

  // staging mapping: thread covers 8 contiguous k's of one row
  const int srow = tid >> 2;          // 0..63
  const int sk0  = (tid & 3) << 3;    // 0,8,16,24
  int agrow = row0 + srow;
  if (agrow >= M) agrow = M - 1;      // clamp; results discarded in epilogue
  const float* aRow = x + (size_t)agrow * 256 + sk0;
  const float* bRow = W + (size_t)srow * 256 + sk0;

  for (int kt = 0; kt < 8; ++kt) {
    const int kb = kt * 32;
    // stage A: 64x32 f32 -> bf16
    {
      float4 v0 = *(const float4*)(aRow + kb);
      float4 v1 = *(const float4*)(aRow + kb + 4);
      bf16x8 u;
      u[0] = (short)f32_to_bf16(v0.x); u[1] = (short)f32_to_bf16(v0.y);
      u[2] = (short)f32_to_bf16(v0.z); u[3] = (short)f32_to_bf16(v0.w);
      u[4] = (short)f32_to_bf16(v1.x); u[5] = (short)f32_to_bf16(v1.y);
      u[6] = (short)f32_to_bf16(v1.z); u[7] = (short)f32_to_bf16(v1.w);
      *(bf16x8*)(&As[srow * 32 + sk0]) = u;
    }
    // stage B: 256x32 (W rows = output cols)
#pragma unroll
    for (int j = 0; j < 4; ++j) {
      const float* p = bRow + (size_t)(j * 64) * 256 + kb;
      float4 v0 = *(const float4*)p;
      float4 v1 = *(const float4*)(p + 4);
      bf16x8 u;
      u[0] = (short)f32_to_bf16(v0.x); u[1] = (short)f32_to_bf16(v0.y);
      u[2] = (short)f32_to_bf16(v0.z); u[3] = (short)f32_to_bf16(v0.w);
      u[4] = (short)f32_to_bf16(v1.x); u[5] = (short)f32_to_bf16(v1.y);
      u[6] = (short)f32_to_bf16(v1.z); u[7] = (short)f32_to_bf16(v1.w);
      *(bf16x8*)(&Bs[(j * 64 + srow) * 32 + sk0]) = u;
    }
    __syncthreads();

    const int r16 = lane & 15;
    const int qk  = (lane >> 4) << 3;  // k-offset 0/8/16/24
    bf16x8 af[4], bfr[4];
#pragma unroll
    for (int g = 0; g < 4; ++g)
      af[g] = *(const bf16x8*)(&As[(g * 16 + r16) * 32 + qk]);
#pragma unroll
    for (int g = 0; g < 4; ++g)
      bfr[g] = *(const bf16x8*)(&Bs[(wid * 64 + g * 16 + r16) * 32 + qk]);
#pragma unroll
    for (int rg = 0; rg < 4; ++rg)
#pragma unroll
      for (int cg = 0; cg < 4; ++cg)
        acc[rg][cg] = __builtin_amdgcn_mfma_f32_16x16x32_bf16(
            af[rg], bfr[cg], acc[rg][cg], 0, 0, 0);
    __syncthreads();
  }

  // epilogue: C/D layout col=lane&15, row=(lane>>4)*4+reg
  const int quad = lane >> 4;
  const int c16  = lane & 15;
#pragma unroll
  for (int rg = 0; rg < 4; ++rg) {
#pragma unroll
    for (int r = 0; r < 4; ++r) {
      int grow = row0 + rg * 16 + quad * 4 + r;
      if (grow >= M) continue;
#pragma unroll
      for (int cg = 0; cg < 4; ++cg) {
        int col = wid * 64 + cg * 16 + c16;
        float v = acc[rg][cg][r] + bias[col];
        if (grow == 0) v = 0.0f;  // padding row
        h[(size_t)grow * 256 + col] = f32_to_bf16(v);
      }
    }
  }
}

// out[i] = relu(h[i] + sum_k h[b_from_a[a_from_b[i,k]]]); one wave per atom.
__global__ __launch_bounds__(256, 4) void gin_gather(
    const unsigned short* __restrict__ h, const int* __restrict__ b_from_a,
    const int* __restrict__ a_from_b, float* __restrict__ out, int N) {
  const int wid  = threadIdx.x >> 6;
  const int lane = threadIdx.x & 63;
  const int i = blockIdx.x * 4 + wid;
  if (i >= N) return;

  int src = 0;
  if (lane < 16) src = b_from_a[a_from_b[i * 16 + lane]];

  const int c0 = lane << 2;  // 4 cols per lane
  uint2 u = *(const uint2*)(h + (size_t)i * 256 + c0);
  float a0 = bf16lo_to_f32(u.x), a1 = bf16hi_to_f32(u.x);
  float a2 = bf16lo_to_f32(u.y), a3 = bf16hi_to_f32(u.y);
#pragma unroll
  for (int k = 0; k < 16; ++k) {
    int s = __shfl(src, k, 64);
    uint2 v = *(const uint2*)(h + (size_t)s * 256 + c0);
    a0 += bf16lo_to_f32(v.x); a1 += bf16hi_to_f32(v.x);
    a2 += bf16lo_to_f32(v.y); a3 += bf16hi_to_f32(v.y);
  }
  float4 r;
  r.x = fmaxf(a0, 0.0f); r.y = fmaxf(a1, 0.0f);
  r.z = fmaxf(a2, 0.0f); r.w = fmaxf(a3, 0.0f);
  *(float4*)(out + (size_t)i * 256 + c0) = r;
}

extern "C" void kernel_launch(void* const* d_in, const int* in_sizes, int n_in,
                              void* d_out, int out_size, void* d_ws, size_t ws_size,
                              hipStream_t stream) {
  const float* x        = (const float*)d_in[0];
  const float* W        = (const float*)d_in[1];
  const float* b        = (const float*)d_in[2];
  const int*   b_from_a = (const int*)d_in[3];
  const int*   a_from_b = (const int*)d_in[4];
  float*       out      = (float*)d_out;
  const int M = in_sizes[0] / 256;  // 50000 atoms

  unsigned short* h = (unsigned short*)d_ws;  // bf16 h, 25.6 MB

  gin_gemm<<<(M + 63) / 64, 256, 0, stream>>>(x, W, b, h, M);
  gin_gather<<<(M + 3) / 4, 256, 0, stream>>>(h, b_from_a, a_from_b, out, M);
}